// Round 1
// baseline (82.606 us; speedup 1.0000x reference)
//
#include <hip/hip_runtime.h>
#include <stdint.h>

namespace {

constexpr int H = 512, W = 512;
constexpr int PLANE = H * W;
constexpr int IMG3 = 3 * PLANE;

constexpr float U_LO = -0.436f, U_HI = 0.436f;
constexpr float V_LO = -0.615f, V_HI = 0.615f;
constexpr float NBINS = 64.0f;   // 6-bit keys

constexpr int TW = 64, TH = 16;  // output tile per block (4 px/thread in x)
constexpr int CW = 72, CH = 24;  // staged tile incl. halo 4
constexpr int US = 19;           // u32 stride of U/V byte planes (76 B, 72 used)
constexpr int LUMS = 73;         // lumT f32 row stride

__device__ __forceinline__ int refl(int i, int n) {
    i = (i < 0) ? (-1 - i) : i;
    return (i >= n) ? (2 * n - 1 - i) : i;
}
__device__ __forceinline__ void cas(float& a, float& b) {
    float t = fminf(a, b); b = fmaxf(a, b); a = t;
}
__device__ __forceinline__ float med3(float a, float b, float c) {
    return fmaxf(fminf(a, b), fminf(fmaxf(a, b), c));
}

__device__ __forceinline__ uint32_t fsh(uint32_t w1, uint32_t w0, uint32_t sh) {
    return (uint32_t)(((((uint64_t)w1) << 32) | w0) >> sh);  // v_alignbit_b32
}

__device__ __forceinline__ uint32_t sadacc(uint32_t t, uint32_t acc) {
#if __has_builtin(__builtin_amdgcn_sad_u8)
    return __builtin_amdgcn_sad_u8(t, 0u, acc);  // acc += 0x80 * #set-bytes
#else
    return acc + (t >> 7);
#endif
}
__device__ __forceinline__ uint32_t cntscaled(uint32_t acc) {
#if __has_builtin(__builtin_amdgcn_sad_u8)
    return acc;                                   // already 128*count
#else
    return ((acc * 0x01010101u) >> 24) << 7;
#endif
}

__device__ __forceinline__ uint32_t permb(uint32_t hi, uint32_t lo, uint32_t sel) {
#if __has_builtin(__builtin_amdgcn_perm)
    return __builtin_amdgcn_perm(hi, lo, sel);
#else
    uint32_t r = 0;
#pragma unroll
    for (int b = 0; b < 4; ++b) {
        uint32_t s = (sel >> (8 * b)) & 7u;
        uint32_t byte = ((s < 4u) ? (lo >> (8 * s)) : (hi >> (8 * (s - 4u)))) & 0xFFu;
        r |= byte << (8 * b);
    }
    return r;
#endif
}

// 16-bin coarse select. ELo bytes = bins 0,2,4,6; EHi = 1,3,5,7;
// OLo = 8,10,12,14; OHi = 9,11,13,15 (counts <= 81).
// Returns coarse bin (0..15) containing 0-based rank 40.
__device__ __forceinline__ uint32_t coarse_bin16(uint32_t ELo, uint32_t EHi,
                                                 uint32_t OLo, uint32_t OHi) {
    uint32_t w0 = permb(EHi, ELo, 0x05010400u);  // bins 0..3
    uint32_t w1 = permb(EHi, ELo, 0x07030602u);  // bins 4..7
    uint32_t w2 = permb(OHi, OLo, 0x05010400u);  // bins 8..11
    uint32_t w3 = permb(OHi, OLo, 0x07030602u);  // bins 12..15
    uint32_t c0 = w0 + (w0 << 8); c0 += c0 << 16;  // in-word prefix sums
    uint32_t c1 = w1 + (w1 << 8); c1 += c1 << 16;
    uint32_t c2 = w2 + (w2 << 8); c2 += c2 << 16;
    uint32_t c3 = w3 + (w3 << 8); c3 += c3 << 16;
    uint32_t t = (c0 >> 24) * 0x01010101u;          // cascade running totals
    c1 += t;
    t = (c1 >> 24) * 0x01010101u;
    c2 += t;
    t = (c2 >> 24) * 0x01010101u;
    c3 += t;
    uint32_t f0 = (0xA8A8A8A8u - c0) & 0x80808080u;  // bit7: cum <= 40
    uint32_t f1 = (0xA8A8A8A8u - c1) & 0x80808080u;
    uint32_t f2 = (0xA8A8A8A8u - c2) & 0x80808080u;
    uint32_t f3 = (0xA8A8A8A8u - c3) & 0x80808080u;
    uint32_t s = sadacc(f3, sadacc(f2, sadacc(f1, sadacc(f0, 0u))));
    return cntscaled(s) >> 7;                        // #bins with cum<41 = bin
}

// Build two pixels' 21-word windows (81 bytes + 3 zero pads each) directly
// from the LDS byte plane (9 rows x 3 words each, re-read per pair).
// Keeps peak live registers at ~45 words (vs 69 when caching rw[27]).
__device__ __forceinline__ void buildPair(const uint32_t* __restrict__ plane,
                                          int rbase, int tx,
                                          uint32_t sA, uint32_t sB,
                                          uint32_t* PA, uint32_t* PB) {
    uint32_t a01 = 0, a1 = 0, a2 = 0;
    uint32_t b01 = 0, b1 = 0, b2 = 0;
#pragma unroll
    for (int r = 0; r < 9; ++r) {
        const uint32_t* row = plane + (rbase + r) * US + tx;
        uint32_t w0 = row[0], w1 = row[1], w2 = row[2];
        PA[2 * r]     = fsh(w1, w0, sA);   // sA==0 folds to w0
        PA[2 * r + 1] = fsh(w2, w1, sA);
        PB[2 * r]     = fsh(w1, w0, sB);
        PB[2 * r + 1] = fsh(w2, w1, sB);
        uint32_t lA = (w2 >> sA) & 0xFFu;  // 9th byte of the window row
        uint32_t lB = (w2 >> sB) & 0xFFu;
        if (r < 4)      { a01 |= lA << (8 * r);       b01 |= lB << (8 * r); }
        else if (r < 8) { a1  |= lA << (8 * (r - 4)); b1  |= lB << (8 * (r - 4)); }
        else            { a2 = lA;                    b2 = lB; }
    }
    PA[18] = a01; PA[19] = a1; PA[20] = a2;  // pads 0x00 always count -> thr 44
    PB[18] = b01; PB[19] = b1; PB[20] = b2;
}

// two interleaved 2-step fine selections over 4 values from coarse bins b0,b1
// (4 independent SAD accumulator chains for ILP)
__device__ __forceinline__ void fine2(const uint32_t* __restrict__ P0,
                                      const uint32_t* __restrict__ P1,
                                      uint32_t b0, uint32_t b1,
                                      uint32_t& k0, uint32_t& k1) {
    uint32_t lo0 = b0 << 2, lo1 = b1 << 2;
    uint32_t t0 = (lo0 + 1u) * 0x01010101u;
    uint32_t t1 = (lo1 + 1u) * 0x01010101u;
    uint32_t c0 = t0 + 0x80808080u, c1 = t1 + 0x80808080u;
    const uint32_t T = 44u * 128u;  // rank 40 + 1 (0-based->count) + 3 pads
#pragma unroll
    for (int s = 2; s >= 1; s >>= 1) {
        uint32_t a0 = 0, a1 = 0, a2 = 0, a3 = 0;
#pragma unroll
        for (int i = 0; i < 10; ++i) {
            a0 = sadacc((c0 - P0[i]) & 0x80808080u, a0);
            a1 = sadacc((c1 - P1[i]) & 0x80808080u, a1);
        }
#pragma unroll
        for (int i = 10; i < 21; ++i) {
            a2 = sadacc((c0 - P0[i]) & 0x80808080u, a2);
            a3 = sadacc((c1 - P1[i]) & 0x80808080u, a3);
        }
        bool r0 = cntscaled(a0 + a2) < T;
        bool r1 = cntscaled(a1 + a3) < T;
        lo0 += r0 ? (uint32_t)s : 0u;
        lo1 += r1 ? (uint32_t)s : 0u;
        if (s > 1) {
            const uint32_t d = 0x01010101u;  // s/2 = 1
            c0 = r0 ? c0 + d : c0 - d;
            c1 = r1 ? c1 + d : c1 - d;
        }
    }
    k0 = lo0; k1 = lo1;
}

__global__ __launch_bounds__(256, 4) void denoise_kernel(const float* __restrict__ img,
                                                         float* __restrict__ out) {
    __shared__ uint32_t uP[CH * US];          // U byte plane (6-bit keys)
    __shared__ uint32_t vP[CH * US];          // V byte plane
    __shared__ float lumT[CH * LUMS];
    // 16B-aligned so the coarse phase can read it with ds_read_b128:
    // row base word offset = (ch*16+ty)*144 + 8*tx  -> 32B-aligned.
    __shared__ __align__(16) uint32_t histT[2][16][72][2];  // [ch][yo][x][w]

    const int tid = threadIdx.x;
    const int tx = tid & 15, ty = tid >> 4;
    const int bx = blockIdx.x, by = blockIdx.y, bz = blockIdx.z;
    const float* __restrict__ base = img + (size_t)bz * IMG3;

    uint8_t* u8p = (uint8_t*)uP;
    uint8_t* v8p = (uint8_t*)vP;

    // --- staging: Y + quantized 6-bit U,V byte planes for 72x24 tile ---
    {
        int idx = tid;
#pragma unroll 7
        for (int it = 0; it < 7; ++it) {
            if (idx < CW * CH) {
                int r = idx / CW, c = idx - r * CW;
                int gy = refl(by * TH + r - 4, H);
                int gx = refl(bx * TW + c - 4, W);
                int o = gy * W + gx;
                float R = base[o], G = base[o + PLANE], B = base[o + 2 * PLANE];
                float Y = 0.299f * R + 0.587f * G + 0.114f * B;
                float U = -0.14713f * R - 0.28886f * G + 0.436f * B;
                float V = 0.615f * R - 0.51499f * G - 0.10001f * B;
                int ku = (int)((U - U_LO) * (NBINS / (U_HI - U_LO)));
                int kv = (int)((V - V_LO) * (NBINS / (V_HI - V_LO)));
                ku = min(max(ku, 0), 63);
                kv = min(max(kv, 0), 63);
                lumT[r * LUMS + c] = Y;
                u8p[r * (US * 4) + c] = (uint8_t)ku;
                v8p[r * (US * 4) + c] = (uint8_t)kv;
            }
            idx += 256;
        }
    }
    __syncthreads();

    // --- column histograms: 2ch x 72 cols, 16 sliding 9-row windows each ---
    if (tid < 144) {
        int ch = (tid >= 72) ? 1 : 0;
        int x = tid - ch * 72;
        const uint8_t* p = (ch ? v8p : u8p) + x;
        uint32_t h0 = 0, h1 = 0;
#pragma unroll
        for (int r = 0; r < 9; ++r) {
            uint32_t b = p[76 * r] >> 2;                 // bin 0..15
            uint32_t d = 1u << ((b & 7u) << 2);
            if (b & 8u) h1 += d; else h0 += d;
        }
        histT[ch][0][x][0] = h0;
        histT[ch][0][x][1] = h1;
        for (int i = 1; i < 16; ++i) {
            uint32_t bo = p[76 * (i - 1)] >> 2;
            uint32_t dob = 1u << ((bo & 7u) << 2);
            if (bo & 8u) h1 -= dob; else h0 -= dob;
            uint32_t bi = p[76 * (i + 8)] >> 2;
            uint32_t dib = 1u << ((bi & 7u) << 2);
            if (bi & 8u) h1 += dib; else h0 += dib;
            histT[ch][i][x][0] = h0;
            histT[ch][i][x][1] = h1;
        }
    }
    __syncthreads();

    // --- coarse bins for 4 px x 2 channels (shared-core merge, cols 3..8) ---
    // Read the 24 hist words per channel as 6x ds_read_b128: the scalar-b32
    // pattern was an 8-way bank conflict (word stride 8 across tx); as b128
    // the 8 words/bank equal the instruction's natural beat count (free).
    uint32_t bins[2][4];
    const uint32_t NM = 0x0F0F0F0Fu;
#pragma unroll
    for (int ch = 0; ch < 2; ++ch) {
        const uint32_t* hrow = &histT[ch][ty][4 * tx][0];
        uint32_t hw[24];
#pragma unroll
        for (int k = 0; k < 6; ++k) {
            uint4 q = *reinterpret_cast<const uint4*>(hrow + 4 * k);
            hw[4 * k] = q.x; hw[4 * k + 1] = q.y;
            hw[4 * k + 2] = q.z; hw[4 * k + 3] = q.w;
        }
        uint32_t sEL = 0, sEH = 0, sOL = 0, sOH = 0;
#pragma unroll
        for (int c = 3; c <= 8; ++c) {
            uint32_t h0 = hw[2 * c], h1 = hw[2 * c + 1];
            sEL += h0 & NM; sEH += (h0 >> 4) & NM;
            sOL += h1 & NM; sOH += (h1 >> 4) & NM;
        }
        uint32_t EL[6], EH[6], OL[6], OH[6];  // edge cols 0,1,2,9,10,11
#pragma unroll
        for (int j = 0; j < 6; ++j) {
            int c = (j < 3) ? j : (j + 6);
            uint32_t h0 = hw[2 * c], h1 = hw[2 * c + 1];
            EL[j] = h0 & NM; EH[j] = (h0 >> 4) & NM;
            OL[j] = h1 & NM; OH[j] = (h1 >> 4) & NM;
        }
        bins[ch][0] = coarse_bin16(sEL + EL[0] + EL[1] + EL[2],
                                   sEH + EH[0] + EH[1] + EH[2],
                                   sOL + OL[0] + OL[1] + OL[2],
                                   sOH + OH[0] + OH[1] + OH[2]);
        bins[ch][1] = coarse_bin16(sEL + EL[1] + EL[2] + EL[3],
                                   sEH + EH[1] + EH[2] + EH[3],
                                   sOL + OL[1] + OL[2] + OL[3],
                                   sOH + OH[1] + OH[2] + OH[3]);
        bins[ch][2] = coarse_bin16(sEL + EL[2] + EL[3] + EL[4],
                                   sEH + EH[2] + EH[3] + EH[4],
                                   sOL + OL[2] + OL[3] + OL[4],
                                   sOH + OH[2] + OH[3] + OH[4]);
        bins[ch][3] = coarse_bin16(sEL + EL[3] + EL[4] + EL[5],
                                   sEH + EH[3] + EH[4] + EH[5],
                                   sOL + OL[3] + OL[4] + OL[5],
                                   sOH + OH[3] + OH[4] + OH[5]);
    }

    // --- fine phase: per channel, 2 pixel-pairs; windows rebuilt from LDS
    //     per pair so no rw[27] cache stays live across fine2 (VGPR relief) ---
    uint32_t kk[2][4];
#pragma unroll
    for (int ch = 0; ch < 2; ++ch) {
        const uint32_t* plane = ch ? vP : uP;
        uint32_t P0[21], P1[21];
        buildPair(plane, ty, tx, 0u, 8u, P0, P1);
        fine2(P0, P1, bins[ch][0], bins[ch][1], kk[ch][0], kk[ch][1]);
        buildPair(plane, ty, tx, 16u, 24u, P0, P1);
        fine2(P0, P1, bins[ch][2], bins[ch][3], kk[ch][2], kk[ch][3]);
    }

    // --- 3x3 lum median for 4 px via shared column sorts (cols 4tx+3..4tx+8) ---
    float Ym[4];
    {
        const float* lp = &lumT[(ty + 3) * LUMS + 4 * tx + 3];
        float lo[6], mi[6], hi[6];
#pragma unroll
        for (int j = 0; j < 6; ++j) {
            float a = lp[j], b = lp[j + LUMS], c = lp[j + 2 * LUMS];
            cas(a, b); cas(b, c); cas(a, b);
            lo[j] = a; mi[j] = b; hi[j] = c;
        }
#pragma unroll
        for (int p = 0; p < 4; ++p) {
            float mx = fmaxf(fmaxf(lo[p], lo[p + 1]), lo[p + 2]);
            float md = med3(mi[p], mi[p + 1], mi[p + 2]);
            float mn = fminf(fminf(hi[p], hi[p + 1]), hi[p + 2]);
            Ym[p] = fminf(fmaxf(med3(mx, md, mn), 0.0f), 1.0f);
        }
    }

    // --- dequant (bin centers) + YUV->RGB + float4 stores ---
    const float us = (U_HI - U_LO) / NBINS, vs = (V_HI - V_LO) / NBINS;
    float4 Rq, Gq, Bq;
    float* Rp = &Rq.x; float* Gp = &Gq.x; float* Bp = &Bq.x;
#pragma unroll
    for (int p = 0; p < 4; ++p) {
        float Um = U_LO + ((float)kk[0][p] + 0.5f) * us;
        float Vm = V_LO + ((float)kk[1][p] + 0.5f) * vs;
        Rp[p] = Ym[p] + 1.13983f * Vm;
        Gp[p] = Ym[p] - 0.39465f * Um - 0.5806f * Vm;
        Bp[p] = Ym[p] + 2.03211f * Um;
    }
    size_t o = (size_t)bz * IMG3 + (size_t)(by * TH + ty) * W + (bx * TW + 4 * tx);
    *(float4*)(out + o) = Rq;
    *(float4*)(out + o + PLANE) = Gq;
    *(float4*)(out + o + 2 * PLANE) = Bq;
}

} // namespace

extern "C" void kernel_launch(void* const* d_in, const int* in_sizes, int n_in,
                              void* d_out, int out_size, void* d_ws, size_t ws_size,
                              hipStream_t stream) {
    const float* img = (const float*)d_in[0];
    float* out = (float*)d_out;
    int batch = in_sizes[0] / IMG3;  // = 4
    dim3 grid(W / TW, H / TH, batch);
    dim3 block(256);
    hipLaunchKernelGGL(denoise_kernel, grid, block, 0, stream, img, out);
}

// Round 2
// 82.494 us; speedup vs baseline: 1.0013x; 1.0013x over previous
//
#include <hip/hip_runtime.h>
#include <stdint.h>

namespace {

constexpr int H = 512, W = 512;
constexpr int PLANE = H * W;
constexpr int IMG3 = 3 * PLANE;

constexpr float U_LO = -0.436f, U_HI = 0.436f;
constexpr float V_LO = -0.615f, V_HI = 0.615f;
constexpr float NBINS = 64.0f;   // 6-bit keys

constexpr int TW = 64, TH = 16;  // output tile per block (4 px/thread in x)
constexpr int CW = 72, CH = 24;  // staged tile incl. halo 4
constexpr int US = 19;           // u32 stride of U/V byte planes (76 B, 72 used)
constexpr int LUMS = 73;         // lumT f32 row stride (odd => conflict-free median reads)

__device__ __forceinline__ int refl(int i, int n) {
    i = (i < 0) ? (-1 - i) : i;
    return (i >= n) ? (2 * n - 1 - i) : i;
}
__device__ __forceinline__ void cas(float& a, float& b) {
    float t = fminf(a, b); b = fmaxf(a, b); a = t;
}
__device__ __forceinline__ float med3(float a, float b, float c) {
    return fmaxf(fminf(a, b), fminf(fmaxf(a, b), c));
}

__device__ __forceinline__ uint32_t sadacc(uint32_t t, uint32_t acc) {
#if __has_builtin(__builtin_amdgcn_sad_u8)
    return __builtin_amdgcn_sad_u8(t, 0u, acc);  // acc += 0x80 * #set-bytes
#else
    return acc + (t >> 7);
#endif
}
__device__ __forceinline__ uint32_t cntscaled(uint32_t acc) {
#if __has_builtin(__builtin_amdgcn_sad_u8)
    return acc;                                   // already 128*count
#else
    return ((acc * 0x01010101u) >> 24) << 7;
#endif
}

__device__ __forceinline__ uint32_t permb(uint32_t hi, uint32_t lo, uint32_t sel) {
#if __has_builtin(__builtin_amdgcn_perm)
    return __builtin_amdgcn_perm(hi, lo, sel);
#else
    uint32_t r = 0;
#pragma unroll
    for (int b = 0; b < 4; ++b) {
        uint32_t s = (sel >> (8 * b)) & 7u;
        uint32_t byte = ((s < 4u) ? (lo >> (8 * s)) : (hi >> (8 * (s - 4u)))) & 0xFFu;
        r |= byte << (8 * b);
    }
    return r;
#endif
}

// 16-bin coarse select. ELo bytes = bins 0,2,4,6; EHi = 1,3,5,7;
// OLo = 8,10,12,14; OHi = 9,11,13,15 (counts <= 81).
// Returns coarse bin (0..15) containing 0-based rank 40.
__device__ __forceinline__ uint32_t coarse_bin16(uint32_t ELo, uint32_t EHi,
                                                 uint32_t OLo, uint32_t OHi) {
    uint32_t w0 = permb(EHi, ELo, 0x05010400u);  // bins 0..3
    uint32_t w1 = permb(EHi, ELo, 0x07030602u);  // bins 4..7
    uint32_t w2 = permb(OHi, OLo, 0x05010400u);  // bins 8..11
    uint32_t w3 = permb(OHi, OLo, 0x07030602u);  // bins 12..15
    uint32_t c0 = w0 + (w0 << 8); c0 += c0 << 16;  // in-word prefix sums
    uint32_t c1 = w1 + (w1 << 8); c1 += c1 << 16;
    uint32_t c2 = w2 + (w2 << 8); c2 += c2 << 16;
    uint32_t c3 = w3 + (w3 << 8); c3 += c3 << 16;
    uint32_t t = (c0 >> 24) * 0x01010101u;          // cascade running totals
    c1 += t;
    t = (c1 >> 24) * 0x01010101u;
    c2 += t;
    t = (c2 >> 24) * 0x01010101u;
    c3 += t;
    uint32_t f0 = (0xA8A8A8A8u - c0) & 0x80808080u;  // bit7: cum <= 40
    uint32_t f1 = (0xA8A8A8A8u - c1) & 0x80808080u;
    uint32_t f2 = (0xA8A8A8A8u - c2) & 0x80808080u;
    uint32_t f3 = (0xA8A8A8A8u - c3) & 0x80808080u;
    uint32_t s = sadacc(f3, sadacc(f2, sadacc(f1, sadacc(f0, 0u))));
    return cntscaled(s) >> 7;                        // #bins with cum<41 = bin
}

// Fine selection for 4 pixels directly on the shared 27-word span (12B x 9 rows).
// Pixel p's 9x9 window = span bytes [p, p+9) per row, expressed as fixed byte
// masks on the edge words -- no materialized P windows, no buildP shifts.
// Keys <= 63, c bytes >= 0x81  =>  the 32-bit subtract is borrow-free per byte.
__device__ __forceinline__ void fine4(const uint32_t* __restrict__ rw,
                                      const uint32_t* __restrict__ bins4,
                                      uint32_t* __restrict__ kk) {
    uint32_t lo0 = bins4[0] << 2, lo1 = bins4[1] << 2;
    uint32_t lo2 = bins4[2] << 2, lo3 = bins4[3] << 2;
    uint32_t c0 = (lo0 + 1u) * 0x01010101u + 0x80808080u;
    uint32_t c1 = (lo1 + 1u) * 0x01010101u + 0x80808080u;
    uint32_t c2 = (lo2 + 1u) * 0x01010101u + 0x80808080u;
    uint32_t c3 = (lo3 + 1u) * 0x01010101u + 0x80808080u;
    const uint32_t T = 41u * 128u;  // count(<= lo) threshold, 81 real bytes
    const uint32_t M0_1 = 0x80808000u, M0_2 = 0x80800000u, M0_3 = 0x80000000u;
    const uint32_t M2_0 = 0x00000080u, M2_1 = 0x00008080u, M2_2 = 0x00808080u;
#pragma unroll
    for (int s = 2; s >= 1; s >>= 1) {
        uint32_t a0 = 0, a1 = 0, a2 = 0, a3 = 0;   // edge-word chains
        uint32_t b0 = 0, b1 = 0, b2 = 0, b3 = 0;   // middle-word chains
#pragma unroll
        for (int r = 0; r < 9; ++r) {
            uint32_t w0 = rw[3 * r], w1 = rw[3 * r + 1], w2 = rw[3 * r + 2];
            a0 = sadacc((c0 - w0) & 0x80808080u, a0);
            a1 = sadacc((c1 - w0) & M0_1, a1);
            a2 = sadacc((c2 - w0) & M0_2, a2);
            a3 = sadacc((c3 - w0) & M0_3, a3);
            b0 = sadacc((c0 - w1) & 0x80808080u, b0);
            b1 = sadacc((c1 - w1) & 0x80808080u, b1);
            b2 = sadacc((c2 - w1) & 0x80808080u, b2);
            b3 = sadacc((c3 - w1) & 0x80808080u, b3);
            a0 = sadacc((c0 - w2) & M2_0, a0);
            a1 = sadacc((c1 - w2) & M2_1, a1);
            a2 = sadacc((c2 - w2) & M2_2, a2);
            a3 = sadacc((c3 - w2) & 0x80808080u, a3);
        }
        bool r0 = cntscaled(a0 + b0) < T;
        bool r1 = cntscaled(a1 + b1) < T;
        bool r2 = cntscaled(a2 + b2) < T;
        bool r3 = cntscaled(a3 + b3) < T;
        lo0 += r0 ? (uint32_t)s : 0u;
        lo1 += r1 ? (uint32_t)s : 0u;
        lo2 += r2 ? (uint32_t)s : 0u;
        lo3 += r3 ? (uint32_t)s : 0u;
        if (s > 1) {
            const uint32_t d = 0x01010101u;
            c0 = r0 ? c0 + d : c0 - d;
            c1 = r1 ? c1 + d : c1 - d;
            c2 = r2 ? c2 + d : c2 - d;
            c3 = r3 ? c3 + d : c3 - d;
        }
    }
    kk[0] = lo0; kk[1] = lo1; kk[2] = lo2; kk[3] = lo3;
}

__global__ __launch_bounds__(256, 4) void denoise_kernel(const float* __restrict__ img,
                                                         float* __restrict__ out) {
    __shared__ uint32_t uP[CH * US];          // U byte plane (6-bit keys)
    __shared__ uint32_t vP[CH * US];          // V byte plane
    __shared__ float lumT[CH * LUMS];
    __shared__ __align__(16) uint32_t histT[2][16][72][2];  // [ch][yo][x][w]

    const int tid = threadIdx.x;
    const int tx = tid & 15, ty = tid >> 4;
    const int bx = blockIdx.x, by = blockIdx.y, bz = blockIdx.z;
    const float* __restrict__ base = img + (size_t)bz * IMG3;

    uint8_t* u8p = (uint8_t*)uP;
    uint8_t* v8p = (uint8_t*)vP;

    // --- staging: Y + quantized 6-bit U,V byte planes for 72x24 tile ---
    const bool interior = (bx >= 1) && (bx <= 6) && (by >= 1) && (by <= 30);
    if (interior) {
        // vectorized: 432 units of (row, 4 consecutive px); float4 loads,
        // packed u32 chroma-key writes (word-aligned: byte addr r*76 + 4u).
        int unit = tid;
#pragma unroll 2
        for (int it = 0; it < 2; ++it, unit += 256) {
            if (unit < 18 * CH) {
                int r = unit / 18, u = unit - r * 18;
                const float* p0 = base + (size_t)((by * TH + r - 4) * W + (bx * TW + 4 * u - 4));
                float4 Rv = *(const float4*)p0;
                float4 Gv = *(const float4*)(p0 + PLANE);
                float4 Bv = *(const float4*)(p0 + 2 * PLANE);
                const float* Rf = &Rv.x; const float* Gf = &Gv.x; const float* Bf = &Bv.x;
                uint32_t kuw = 0, kvw = 0;
                float Yq[4];
#pragma unroll
                for (int j = 0; j < 4; ++j) {
                    float R = Rf[j], G = Gf[j], B = Bf[j];
                    float Y = 0.299f * R + 0.587f * G + 0.114f * B;
                    float U = -0.14713f * R - 0.28886f * G + 0.436f * B;
                    float V = 0.615f * R - 0.51499f * G - 0.10001f * B;
                    int ku = (int)((U - U_LO) * (NBINS / (U_HI - U_LO)));
                    int kv = (int)((V - V_LO) * (NBINS / (V_HI - V_LO)));
                    ku = min(max(ku, 0), 63);
                    kv = min(max(kv, 0), 63);
                    kuw |= (uint32_t)ku << (8 * j);
                    kvw |= (uint32_t)kv << (8 * j);
                    Yq[j] = Y;
                }
                uP[r * US + u] = kuw;
                vP[r * US + u] = kvw;
                float* lrow = &lumT[r * LUMS + 4 * u];
                lrow[0] = Yq[0]; lrow[1] = Yq[1]; lrow[2] = Yq[2]; lrow[3] = Yq[3];
            }
        }
    } else {
        int idx = tid;
#pragma unroll 7
        for (int it = 0; it < 7; ++it) {
            if (idx < CW * CH) {
                int r = idx / CW, c = idx - r * CW;
                int gy = refl(by * TH + r - 4, H);
                int gx = refl(bx * TW + c - 4, W);
                int o = gy * W + gx;
                float R = base[o], G = base[o + PLANE], B = base[o + 2 * PLANE];
                float Y = 0.299f * R + 0.587f * G + 0.114f * B;
                float U = -0.14713f * R - 0.28886f * G + 0.436f * B;
                float V = 0.615f * R - 0.51499f * G - 0.10001f * B;
                int ku = (int)((U - U_LO) * (NBINS / (U_HI - U_LO)));
                int kv = (int)((V - V_LO) * (NBINS / (V_HI - V_LO)));
                ku = min(max(ku, 0), 63);
                kv = min(max(kv, 0), 63);
                lumT[r * LUMS + c] = Y;
                u8p[r * (US * 4) + c] = (uint8_t)ku;
                v8p[r * (US * 4) + c] = (uint8_t)kv;
            }
            idx += 256;
        }
    }
    __syncthreads();

    // --- column histograms: 2ch x 72 cols, 16 sliding 9-row windows each ---
    if (tid < 144) {
        int ch = (tid >= 72) ? 1 : 0;
        int x = tid - ch * 72;
        const uint8_t* p = (ch ? v8p : u8p) + x;
        uint32_t h0 = 0, h1 = 0;
#pragma unroll
        for (int r = 0; r < 9; ++r) {
            uint32_t b = p[76 * r] >> 2;                 // bin 0..15
            uint32_t d = 1u << ((b & 7u) << 2);
            if (b & 8u) h1 += d; else h0 += d;
        }
        histT[ch][0][x][0] = h0;
        histT[ch][0][x][1] = h1;
        for (int i = 1; i < 16; ++i) {
            uint32_t bo = p[76 * (i - 1)] >> 2;
            uint32_t dob = 1u << ((bo & 7u) << 2);
            if (bo & 8u) h1 -= dob; else h0 -= dob;
            uint32_t bi = p[76 * (i + 8)] >> 2;
            uint32_t dib = 1u << ((bi & 7u) << 2);
            if (bi & 8u) h1 += dib; else h0 += dib;
            histT[ch][i][x][0] = h0;
            histT[ch][i][x][1] = h1;
        }
    }
    __syncthreads();

    // --- coarse bins for 4 px x 2 channels (shared-core merge, cols 3..8) ---
    uint32_t bins[2][4];
    const uint32_t NM = 0x0F0F0F0Fu;
#pragma unroll
    for (int ch = 0; ch < 2; ++ch) {
        const uint32_t* hrow = &histT[ch][ty][4 * tx][0];
        uint32_t hw[24];
#pragma unroll
        for (int k = 0; k < 6; ++k) {
            uint4 q = *reinterpret_cast<const uint4*>(hrow + 4 * k);
            hw[4 * k] = q.x; hw[4 * k + 1] = q.y;
            hw[4 * k + 2] = q.z; hw[4 * k + 3] = q.w;
        }
        uint32_t sEL = 0, sEH = 0, sOL = 0, sOH = 0;
#pragma unroll
        for (int c = 3; c <= 8; ++c) {
            uint32_t h0 = hw[2 * c], h1 = hw[2 * c + 1];
            sEL += h0 & NM; sEH += (h0 >> 4) & NM;
            sOL += h1 & NM; sOH += (h1 >> 4) & NM;
        }
        uint32_t EL[6], EH[6], OL[6], OH[6];  // edge cols 0,1,2,9,10,11
#pragma unroll
        for (int j = 0; j < 6; ++j) {
            int c = (j < 3) ? j : (j + 6);
            uint32_t h0 = hw[2 * c], h1 = hw[2 * c + 1];
            EL[j] = h0 & NM; EH[j] = (h0 >> 4) & NM;
            OL[j] = h1 & NM; OH[j] = (h1 >> 4) & NM;
        }
        bins[ch][0] = coarse_bin16(sEL + EL[0] + EL[1] + EL[2],
                                   sEH + EH[0] + EH[1] + EH[2],
                                   sOL + OL[0] + OL[1] + OL[2],
                                   sOH + OH[0] + OH[1] + OH[2]);
        bins[ch][1] = coarse_bin16(sEL + EL[1] + EL[2] + EL[3],
                                   sEH + EH[1] + EH[2] + EH[3],
                                   sOL + OL[1] + OL[2] + OL[3],
                                   sOH + OH[1] + OH[2] + OH[3]);
        bins[ch][2] = coarse_bin16(sEL + EL[2] + EL[3] + EL[4],
                                   sEH + EH[2] + EH[3] + EH[4],
                                   sOL + OL[2] + OL[3] + OL[4],
                                   sOH + OH[2] + OH[3] + OH[4]);
        bins[ch][3] = coarse_bin16(sEL + EL[3] + EL[4] + EL[5],
                                   sEH + EH[3] + EH[4] + EH[5],
                                   sOL + OL[3] + OL[4] + OL[5],
                                   sOH + OH[3] + OH[4] + OH[5]);
    }

    // --- fine phase: per channel, masked SAD directly on the 27-word span ---
    uint32_t kk[2][4];
#pragma unroll
    for (int ch = 0; ch < 2; ++ch) {
        const uint32_t* plane = ch ? vP : uP;
        uint32_t rw[27];
#pragma unroll
        for (int r = 0; r < 9; ++r) {
            const uint32_t* row = plane + (ty + r) * US + tx;
            rw[3 * r] = row[0]; rw[3 * r + 1] = row[1]; rw[3 * r + 2] = row[2];
        }
        fine4(rw, bins[ch], kk[ch]);
    }

    // --- 3x3 lum median for 4 px via shared column sorts (cols 4tx+3..4tx+8) ---
    float Ym[4];
    {
        const float* lp = &lumT[(ty + 3) * LUMS + 4 * tx + 3];
        float lo[6], mi[6], hi[6];
#pragma unroll
        for (int j = 0; j < 6; ++j) {
            float a = lp[j], b = lp[j + LUMS], c = lp[j + 2 * LUMS];
            cas(a, b); cas(b, c); cas(a, b);
            lo[j] = a; mi[j] = b; hi[j] = c;
        }
#pragma unroll
        for (int p = 0; p < 4; ++p) {
            float mx = fmaxf(fmaxf(lo[p], lo[p + 1]), lo[p + 2]);
            float md = med3(mi[p], mi[p + 1], mi[p + 2]);
            float mn = fminf(fminf(hi[p], hi[p + 1]), hi[p + 2]);
            Ym[p] = fminf(fmaxf(med3(mx, md, mn), 0.0f), 1.0f);
        }
    }

    // --- dequant (bin centers) + YUV->RGB + float4 stores ---
    const float us = (U_HI - U_LO) / NBINS, vs = (V_HI - V_LO) / NBINS;
    float4 Rq, Gq, Bq;
    float* Rp = &Rq.x; float* Gp = &Gq.x; float* Bp = &Bq.x;
#pragma unroll
    for (int p = 0; p < 4; ++p) {
        float Um = U_LO + ((float)kk[0][p] + 0.5f) * us;
        float Vm = V_LO + ((float)kk[1][p] + 0.5f) * vs;
        Rp[p] = Ym[p] + 1.13983f * Vm;
        Gp[p] = Ym[p] - 0.39465f * Um - 0.5806f * Vm;
        Bp[p] = Ym[p] + 2.03211f * Um;
    }
    size_t o = (size_t)bz * IMG3 + (size_t)(by * TH + ty) * W + (bx * TW + 4 * tx);
    *(float4*)(out + o) = Rq;
    *(float4*)(out + o + PLANE) = Gq;
    *(float4*)(out + o + 2 * PLANE) = Bq;
}

} // namespace

extern "C" void kernel_launch(void* const* d_in, const int* in_sizes, int n_in,
                              void* d_out, int out_size, void* d_ws, size_t ws_size,
                              hipStream_t stream) {
    const float* img = (const float*)d_in[0];
    float* out = (float*)d_out;
    int batch = in_sizes[0] / IMG3;  // = 4
    dim3 grid(W / TW, H / TH, batch);
    dim3 block(256);
    hipLaunchKernelGGL(denoise_kernel, grid, block, 0, stream, img, out);
}